// Round 2
// baseline (221.031 us; speedup 1.0000x reference)
//
#include <hip/hip_runtime.h>
#include <stdint.h>

// minerva2: echo = (F̂ Ê^T)^3 @ V, intensity = rowsum((F̂ Ê^T)^3)
// Fused flash-style bf16 MFMA. R2: T2 XOR-swizzle staging, 32KB LDS,
// grid 1024 (16 D-chunks), wc-merged epilogue.

typedef unsigned short u16;
typedef __bf16 bf16x8 __attribute__((ext_vector_type(8)));
typedef float f32x4 __attribute__((ext_vector_type(4)));
typedef unsigned short u16x4 __attribute__((ext_vector_type(4)));

#define NQ 8192
#define ND 16384
#define NH 256
#define NC 28
#define DCHUNK 1024
#define NDT 8        // 128-wide D-tiles per chunk
#define NSLOT 16     // partial slots = 16 D-chunks (wc merged in-kernel)

__device__ __forceinline__ u16 f2bf(float f) {
  unsigned u = __builtin_bit_cast(unsigned, f);
  u += 0x7fffu + ((u >> 16) & 1u);   // RNE
  return (u16)(u >> 16);
}

__device__ __forceinline__ void gload16(const void* g, void* l) {
  __builtin_amdgcn_global_load_lds(
      (__attribute__((address_space(1))) void*)g,
      (__attribute__((address_space(3))) void*)l, 16, 0, 0);
}

// ---------------- normalize rows of [rows][256] f32 -> bf16 ----------------
__global__ __launch_bounds__(256) void norm_kernel(const float* __restrict__ in,
                                                   u16* __restrict__ out, int rows) {
  const int wid = threadIdx.x >> 6, lane = threadIdx.x & 63;
  const int row = blockIdx.x * 4 + wid;
  if (row >= rows) return;
  const float4* p = (const float4*)(in + (size_t)row * NH);
  float4 v = p[lane];
  float ss = v.x * v.x + v.y * v.y + v.z * v.z + v.w * v.w;
#pragma unroll
  for (int m = 1; m <= 32; m <<= 1) ss += __shfl_xor(ss, m, 64);
  const float sc = 1.0f / fmaxf(sqrtf(ss), 1e-12f);
  u16x4 o;
  o.x = f2bf(v.x * sc); o.y = f2bf(v.y * sc);
  o.z = f2bf(v.z * sc); o.w = f2bf(v.w * sc);
  *(u16x4*)(out + (size_t)row * NH + lane * 4) = o;
}

// ---------------- V [16384][28] f32 -> Vt [32][16384] bf16 (pad cols) ------
__global__ __launch_bounds__(256) void vt_kernel(const float* __restrict__ V,
                                                 u16* __restrict__ Vt) {
  const int d = blockIdx.x * 256 + threadIdx.x;
#pragma unroll
  for (int c = 0; c < NC; ++c) Vt[(size_t)c * ND + d] = f2bf(V[(size_t)d * NC + c]);
#pragma unroll
  for (int c = NC; c < 32; ++c) Vt[(size_t)c * ND + d] = 0;
}

// ---------------- fused main kernel ----------------------------------------
// grid 1024 = 64 ntiles * 16 dchunks; 256 threads = 4 waves (2x2 over 128x128 S)
// LDS 32KB: buf b at [b*16K, b*16K+16K): Q[128][32]bf16 (8KB) + K[128][32] (8KB).
// Rows are 64B = 4 chunks of 16B; chunk swizzle: lds_chunk = g_chunk ^ ((row>>1)&3).
// a-stash aliases buf1: per-wave 4KB at 16K + wid*4K ([64 q][32 d] bf16, swizzled).
__global__ __launch_bounds__(256, 3) void fused_kernel(
    const u16* __restrict__ Qn, const u16* __restrict__ Kn,
    const u16* __restrict__ Vt, float* __restrict__ ep, float* __restrict__ ip) {
  __shared__ alignas(16) char smem[32768];
  const int tid = threadIdx.x;
  const int wid = tid >> 6;
  const int lane = tid & 63;
  const int l16 = lane & 15;
  const int lg = lane >> 4;
  const int wr = wid >> 1;
  const int wc = wid & 1;
  const int ntile = blockIdx.x & 63;
  const int dch = blockIdx.x >> 6;
  const int qbase = ntile * 128;

  f32x4 eacc[4][2];
  f32x4 iacc[4];
  f32x4 sacc[4][4];
#pragma unroll
  for (int mb = 0; mb < 4; ++mb) {
    eacc[mb][0] = f32x4{0.f, 0.f, 0.f, 0.f};
    eacc[mb][1] = f32x4{0.f, 0.f, 0.f, 0.f};
    iacc[mb] = f32x4{0.f, 0.f, 0.f, 0.f};
  }

  // stage one 32-wide H-slab of Q-tile (128 rows) + K-tile into buf
  auto stage = [&](int buf, int h0, int dbase) {
    const int rowq = tid >> 2;                       // 0..63
    const int cg = (tid & 3) ^ ((rowq >> 1) & 3);    // pre-swizzled global chunk
    const u16* gq = Qn + (size_t)(qbase + rowq) * NH + h0 + cg * 8;
    const u16* gk = Kn + (size_t)(dbase + rowq) * NH + h0 + cg * 8;
    char* lq = smem + buf * 16384 + wid * 1024;      // + lane*16 implicit
    gload16(gq, lq);
    gload16(gk, lq + 8192);
    gload16(gq + (size_t)64 * NH, lq + 4096);        // rows 64..127
    gload16(gk + (size_t)64 * NH, lq + 12288);
  };

  const int rswz = (l16 >> 1) & 3;  // (row>>1)&3 for row = *+l16

  auto compute_s = [&](int buf) {
    const char* qb = smem + buf * 16384;
    const char* kb = qb + 8192;
    bf16x8 A[4], B[4];
#pragma unroll
    for (int mb = 0; mb < 4; ++mb)
      A[mb] = *(const bf16x8*)(qb + (wr * 64 + mb * 16 + l16) * 64 + ((lg ^ rswz) << 4));
#pragma unroll
    for (int nb = 0; nb < 4; ++nb)
      B[nb] = *(const bf16x8*)(kb + (wc * 64 + nb * 16 + l16) * 64 + ((lg ^ rswz) << 4));
#pragma unroll
    for (int mb = 0; mb < 4; ++mb)
#pragma unroll
      for (int nb = 0; nb < 4; ++nb)
        sacc[mb][nb] = __builtin_amdgcn_mfma_f32_16x16x32_bf16(
            A[mb], B[nb], sacc[mb][nb], 0, 0, 0);
  };

  stage(0, 0, dch * DCHUNK);
  __syncthreads();

  for (int t = 0; t < NDT; ++t) {
    const int dbase = dch * DCHUNK + t * 128;
#pragma unroll
    for (int mb = 0; mb < 4; ++mb)
#pragma unroll
      for (int nb = 0; nb < 4; ++nb) sacc[mb][nb] = f32x4{0.f, 0.f, 0.f, 0.f};

#pragma unroll
    for (int s = 0; s < 8; ++s) {
      if (s < 7) stage((s + 1) & 1, (s + 1) * 32, dbase);
      else if (t < NDT - 1) stage(0, 0, dbase + 128);
      compute_s(s & 1);
      __syncthreads();
    }
    // buf0 now holds next tile's slab0 (drained); buf1 is free -> a-stash.

    // PV B-frags from global Vt (L2-resident)
    bf16x8 vB[2][2];
    const int dglob = dbase + wc * 64;
#pragma unroll
    for (int dk = 0; dk < 2; ++dk)
#pragma unroll
      for (int cn = 0; cn < 2; ++cn)
        vB[dk][cn] = *(const bf16x8*)(Vt + (size_t)(cn * 16 + l16) * ND +
                                      dglob + dk * 32 + lg * 8);

    char* sb = smem + 16384 + wid * 4096;  // wave-private [64][32] bf16, swizzled
#pragma unroll
    for (int half = 0; half < 2; ++half) {
#pragma unroll
      for (int mb = 0; mb < 4; ++mb) {
#pragma unroll
        for (int nb2 = 0; nb2 < 2; ++nb2) {
          const int nb = half * 2 + nb2;
          f32x4 s = sacc[mb][nb];
          f32x4 a3 = s * s * s;
          iacc[mb] += a3;
          const int c = nb2 * 16 + l16;    // local d-col 0..31
          const int cc = c >> 3;
#pragma unroll
          for (int r = 0; r < 4; ++r) {
            const int row = mb * 16 + lg * 4 + r;
            *(u16*)(sb + row * 64 + (((cc ^ ((lg * 2 + (r >> 1)) & 3)) << 4)) +
                    (c & 7) * 2) = f2bf(a3[r]);
          }
        }
      }
      // PV for this 32-d half (wave-local DS: in-order, no barrier needed)
#pragma unroll
      for (int mb = 0; mb < 4; ++mb) {
        const bf16x8 aA =
            *(const bf16x8*)(sb + (mb * 16 + l16) * 64 + ((lg ^ rswz) << 4));
#pragma unroll
        for (int cn = 0; cn < 2; ++cn)
          eacc[mb][cn] = __builtin_amdgcn_mfma_f32_16x16x32_bf16(
              aA, vB[half][cn], eacc[mb][cn], 0, 0, 0);
      }
    }
    __syncthreads();  // protect stash region before next tile's stage(buf1,...)
  }

  // ---- epilogue: merge wc halves via LDS, write partials (slot = dch) ----
  float ired[4][4];
#pragma unroll
  for (int mb = 0; mb < 4; ++mb)
#pragma unroll
    for (int r = 0; r < 4; ++r) {
      float v = iacc[mb][r];
      v += __shfl_xor(v, 1, 64);
      v += __shfl_xor(v, 2, 64);
      v += __shfl_xor(v, 4, 64);
      v += __shfl_xor(v, 8, 64);
      ired[mb][r] = v;
    }

  float* eml = (float*)smem;               // 128 lanes * 36 dwords = 18KB
  float* iml = (float*)(smem + 18432);     // 128 floats
  if (wc == 1) {
    const int base = (wr * 64 + lane) * 36;
#pragma unroll
    for (int mb = 0; mb < 4; ++mb)
#pragma unroll
      for (int cn = 0; cn < 2; ++cn)
        *(f32x4*)(eml + base + (mb * 2 + cn) * 4) = eacc[mb][cn];
    if (l16 == 0)
#pragma unroll
      for (int mb = 0; mb < 4; ++mb)
#pragma unroll
        for (int r = 0; r < 4; ++r)
          iml[wr * 64 + mb * 16 + lg * 4 + r] = ired[mb][r];
  }
  __syncthreads();
  if (wc == 0) {
    const int slot = dch;
    const int base = (wr * 64 + lane) * 36;
#pragma unroll
    for (int mb = 0; mb < 4; ++mb)
#pragma unroll
      for (int cn = 0; cn < 2; ++cn) {
        f32x4 m = eacc[mb][cn] + *(const f32x4*)(eml + base + (mb * 2 + cn) * 4);
#pragma unroll
        for (int r = 0; r < 4; ++r) {
          const int row = qbase + wr * 64 + mb * 16 + lg * 4 + r;
          ep[((size_t)slot * NQ + row) * 32 + cn * 16 + l16] = m[r];
        }
      }
    if (l16 == 0)
#pragma unroll
      for (int mb = 0; mb < 4; ++mb)
#pragma unroll
        for (int r = 0; r < 4; ++r) {
          const int rloc = wr * 64 + mb * 16 + lg * 4 + r;
          ip[(size_t)slot * NQ + qbase + rloc] = ired[mb][r] + iml[rloc];
        }
  }
}

// ---------------- reduce 16 partial slots -> d_out -------------------------
__global__ __launch_bounds__(256) void reduce_kernel(const float* __restrict__ ep,
                                                     const float* __restrict__ ip,
                                                     float* __restrict__ out) {
  const int g = blockIdx.x * 256 + threadIdx.x;  // 8192*32
  const int q = g >> 5, c = g & 31;
  if (c < NC) {
    float s = 0.f;
#pragma unroll
    for (int k = 0; k < NSLOT; ++k) s += ep[((size_t)k * NQ + q) * 32 + c];
    out[(size_t)q * NC + c] = s;
  } else if (c == NC) {
    float s = 0.f;
#pragma unroll
    for (int k = 0; k < NSLOT; ++k) s += ip[(size_t)k * NQ + q];
    out[(size_t)NQ * NC + q] = s;
  }
}

extern "C" void kernel_launch(void* const* d_in, const int* in_sizes, int n_in,
                              void* d_out, int out_size, void* d_ws, size_t ws_size,
                              hipStream_t stream) {
  const float* feat = (const float*)d_in[0];  // [8192][256]
  const float* exf  = (const float*)d_in[1];  // [16384][256]
  const float* exc  = (const float*)d_in[2];  // [16384][28]
  float* out = (float*)d_out;
  char* ws = (char*)d_ws;
  u16* qn = (u16*)ws;
  u16* kn = (u16*)(ws + 4194304);
  u16* vt = (u16*)(ws + 12582912);
  float* ep = (float*)(ws + 13631488);
  float* ip = (float*)(ws + 30408704);

  norm_kernel<<<dim3(NQ / 4), dim3(256), 0, stream>>>(feat, qn, NQ);
  norm_kernel<<<dim3(ND / 4), dim3(256), 0, stream>>>(exf, kn, ND);
  vt_kernel<<<dim3(ND / 256), dim3(256), 0, stream>>>(exc, vt);
  fused_kernel<<<dim3(1024), dim3(256), 0, stream>>>(qn, kn, vt, ep, ip);
  reduce_kernel<<<dim3(NQ * 32 / 256), dim3(256), 0, stream>>>(ep, ip, out);
}

// Round 3
// 134.390 us; speedup vs baseline: 1.6447x; 1.6447x over previous
//
#include <hip/hip_runtime.h>
#include <stdint.h>

// minerva2: echo = (F̂ Ê^T)^3 @ V, intensity = rowsum((F̂ Ê^T)^3)
// R3 = R1 structure (136us known-good) + T2 XOR swizzle on staging/compute_s
// reads only. Swizzle is both-sides: pre-swizzled global source (rule #21),
// linear global_load_lds dest, XOR'd ds_read addresses.

typedef unsigned short u16;
typedef __bf16 bf16x8 __attribute__((ext_vector_type(8)));
typedef float f32x4 __attribute__((ext_vector_type(4)));
typedef unsigned short u16x4 __attribute__((ext_vector_type(4)));

#define NQ 8192
#define ND 16384
#define NH 256
#define NC 28
#define BM 128
#define BD 128
#define DCHUNK 2048
#define NDT 16       // D-tiles per chunk
#define NSLOT 16     // partial slots = 8 chunks * 2 wc

__device__ __forceinline__ u16 f2bf(float f) {
  unsigned u = __builtin_bit_cast(unsigned, f);
  u += 0x7fffu + ((u >> 16) & 1u);   // RNE
  return (u16)(u >> 16);
}

__device__ __forceinline__ void gload16(const void* g, void* l) {
  // async global->LDS, 16B/lane; LDS dest = wave-uniform base + lane*16
  __builtin_amdgcn_global_load_lds(
      (__attribute__((address_space(1))) void*)g,
      (__attribute__((address_space(3))) void*)l, 16, 0, 0);
}

// ---------------- normalize rows of [rows][256] f32 -> bf16 ----------------
__global__ __launch_bounds__(256) void norm_kernel(const float* __restrict__ in,
                                                   u16* __restrict__ out, int rows) {
  const int wid = threadIdx.x >> 6, lane = threadIdx.x & 63;
  const int row = blockIdx.x * 4 + wid;
  if (row >= rows) return;
  const float4* p = (const float4*)(in + (size_t)row * NH);
  float4 v = p[lane];
  float ss = v.x * v.x + v.y * v.y + v.z * v.z + v.w * v.w;
#pragma unroll
  for (int m = 1; m <= 32; m <<= 1) ss += __shfl_xor(ss, m, 64);
  const float sc = 1.0f / fmaxf(sqrtf(ss), 1e-12f);  // matches F.normalize eps
  u16x4 o;
  o.x = f2bf(v.x * sc); o.y = f2bf(v.y * sc);
  o.z = f2bf(v.z * sc); o.w = f2bf(v.w * sc);
  *(u16x4*)(out + (size_t)row * NH + lane * 4) = o;
}

// ---------------- V [16384][28] f32 -> Vt [32][16384] bf16 (pad cols) ------
__global__ __launch_bounds__(256) void vt_kernel(const float* __restrict__ V,
                                                 u16* __restrict__ Vt) {
  const int d = blockIdx.x * 256 + threadIdx.x;  // 16384
#pragma unroll
  for (int c = 0; c < NC; ++c) Vt[(size_t)c * ND + d] = f2bf(V[(size_t)d * NC + c]);
#pragma unroll
  for (int c = NC; c < 32; ++c) Vt[(size_t)c * ND + d] = 0;
}

// ---------------- fused main kernel ----------------------------------------
// grid 512 = 64 ntiles * 8 dchunks; 256 threads = 4 waves (2x2 over 128x128 S)
__global__ __launch_bounds__(256, 2) void fused_kernel(
    const u16* __restrict__ Qn, const u16* __restrict__ Kn,
    const u16* __restrict__ Vt, float* __restrict__ ep, float* __restrict__ ip) {
  // LDS: Qbuf0 [0,16K) Qbuf1 [16K,32K) Kbuf0 [32K,48K) Kbuf1 [48K,64K)
  // a_lds aliases [0,32K): per-wave 8KB region (safe: barriers separate phases)
  __shared__ alignas(16) char smem[65536];
  const int tid = threadIdx.x;
  const int wid = tid >> 6;
  const int lane = tid & 63;
  const int l16 = lane & 15;
  const int lg = lane >> 4;
  const int wr = wid >> 1;
  const int wc = wid & 1;
  const int ntile = blockIdx.x & 63;
  const int dch = blockIdx.x >> 6;
  const int qbase = ntile * BM;

  f32x4 eacc[4][2];
  float iacc[4][4];
#pragma unroll
  for (int mb = 0; mb < 4; ++mb) {
#pragma unroll
    for (int cn = 0; cn < 2; ++cn) eacc[mb][cn] = f32x4{0.f, 0.f, 0.f, 0.f};
#pragma unroll
    for (int r = 0; r < 4; ++r) iacc[mb][r] = 0.f;
  }

  f32x4 sacc[4][4];

  // stage one 64-wide H-slab of Q-tile and K-tile into buf (row-major [128][8 chunks])
  // swizzle: LDS chunk c holds global chunk c ^ (row&7) (pre-swizzled source)
  auto stage = [&](int buf, int h0, int dbase) {
#pragma unroll
    for (int r = 0; r < 4; ++r) {
      const int row = r * 32 + (tid >> 3);
      const int c8 = (tid & 7) ^ (row & 7);
      gload16(Qn + (size_t)(qbase + row) * NH + h0 + c8 * 8,
              smem + buf * 16384 + r * 4096 + wid * 1024);
      gload16(Kn + (size_t)(dbase + row) * NH + h0 + c8 * 8,
              smem + 32768 + buf * 16384 + r * 4096 + wid * 1024);
    }
  };

  auto compute_s = [&](int buf) {
    const char* qb = smem + buf * 16384;
    const char* kb = smem + 32768 + buf * 16384;
    const int rs = l16 & 7;  // row&7 for rows *+l16
#pragma unroll
    for (int k2 = 0; k2 < 2; ++k2) {
      bf16x8 A[4], B[4];
#pragma unroll
      for (int mb = 0; mb < 4; ++mb)
        A[mb] = *(const bf16x8*)(qb + (wr * 64 + mb * 16 + l16) * 128 +
                                 (((k2 * 4 + lg) ^ rs) << 4));
#pragma unroll
      for (int nb = 0; nb < 4; ++nb)
        B[nb] = *(const bf16x8*)(kb + (wc * 64 + nb * 16 + l16) * 128 +
                                 (((k2 * 4 + lg) ^ rs) << 4));
#pragma unroll
      for (int mb = 0; mb < 4; ++mb)
#pragma unroll
        for (int nb = 0; nb < 4; ++nb)
          sacc[mb][nb] = __builtin_amdgcn_mfma_f32_16x16x32_bf16(
              A[mb], B[nb], sacc[mb][nb], 0, 0, 0);
    }
  };

  for (int t = 0; t < NDT; ++t) {
    const int dbase = dch * DCHUNK + t * BD;
#pragma unroll
    for (int mb = 0; mb < 4; ++mb)
#pragma unroll
      for (int nb = 0; nb < 4; ++nb) sacc[mb][nb] = f32x4{0.f, 0.f, 0.f, 0.f};

    stage(0, 0, dbase);
    __syncthreads();
#pragma unroll
    for (int ks = 0; ks < 4; ++ks) {
      if (ks < 3) stage((ks + 1) & 1, (ks + 1) * 64, dbase);
      compute_s(ks & 1);
      __syncthreads();
    }

    // PV B-frags from global Vt (L2-resident): B[32d x 16c], lane: c=l16, d=lg*8+i
    bf16x8 vB[2][2];
    const int dglob = dbase + wc * 64;
#pragma unroll
    for (int dk = 0; dk < 2; ++dk)
#pragma unroll
      for (int cn = 0; cn < 2; ++cn)
        vB[dk][cn] = *(const bf16x8*)(Vt + (size_t)(cn * 16 + l16) * ND +
                                      dglob + dk * 32 + lg * 8);

    // cube (fp32), accumulate intensity, stash bf16 a into swizzled LDS
    char* aw = smem + wid * 8192;  // per-wave private [64][64] bf16, 16B-chunk XOR swizzle
#pragma unroll
    for (int mb = 0; mb < 4; ++mb) {
#pragma unroll
      for (int nb = 0; nb < 4; ++nb) {
        f32x4 s = sacc[mb][nb];
        f32x4 a3 = s * s * s;
#pragma unroll
        for (int r = 0; r < 4; ++r) {
          iacc[mb][r] += a3[r];
          const int row = mb * 16 + lg * 4 + r;   // C/D layout: row=(lane>>4)*4+reg
          const int col = nb * 16 + l16;          //              col=lane&15
          *(u16*)(aw + row * 128 + (((col >> 3) ^ (row & 7)) << 4) + (col & 7) * 2) =
              f2bf(a3[r]);
        }
      }
    }

    // PV: echo[q, c] += a[q, d] * V[d, c]
#pragma unroll
    for (int mb = 0; mb < 4; ++mb) {
#pragma unroll
      for (int dk = 0; dk < 2; ++dk) {
        const int row = mb * 16 + l16;
        const bf16x8 aA =
            *(const bf16x8*)(aw + row * 128 + (((dk * 4 + lg) ^ (row & 7)) << 4));
#pragma unroll
        for (int cn = 0; cn < 2; ++cn)
          eacc[mb][cn] = __builtin_amdgcn_mfma_f32_16x16x32_bf16(
              aA, vB[dk][cn], eacc[mb][cn], 0, 0, 0);
      }
    }
    __syncthreads();  // a_lds reads done before next tile's staging overwrites
  }

  // ---- epilogue: write partials (slot = dch*2 + wc) ----
  const int slot = dch * 2 + wc;
#pragma unroll
  for (int mb = 0; mb < 4; ++mb) {
#pragma unroll
    for (int r = 0; r < 4; ++r) {
      float v = iacc[mb][r];
      v += __shfl_xor(v, 1, 64);
      v += __shfl_xor(v, 2, 64);
      v += __shfl_xor(v, 4, 64);
      v += __shfl_xor(v, 8, 64);
      if (l16 == 0) {
        const int row = qbase + wr * 64 + mb * 16 + lg * 4 + r;
        ip[(size_t)slot * NQ + row] = v;
      }
    }
  }
#pragma unroll
  for (int mb = 0; mb < 4; ++mb)
#pragma unroll
    for (int cn = 0; cn < 2; ++cn)
#pragma unroll
      for (int r = 0; r < 4; ++r) {
        const int row = qbase + wr * 64 + mb * 16 + lg * 4 + r;
        const int col = cn * 16 + l16;
        ep[((size_t)slot * NQ + row) * 32 + col] = eacc[mb][cn][r];
      }
}

// ---------------- reduce 16 partial slots -> d_out -------------------------
__global__ __launch_bounds__(256) void reduce_kernel(const float* __restrict__ ep,
                                                     const float* __restrict__ ip,
                                                     float* __restrict__ out) {
  const int g = blockIdx.x * 256 + threadIdx.x;  // 8192*32
  const int q = g >> 5, c = g & 31;
  if (c < NC) {
    float s = 0.f;
#pragma unroll
    for (int k = 0; k < NSLOT; ++k) s += ep[((size_t)k * NQ + q) * 32 + c];
    out[(size_t)q * NC + c] = s;
  } else if (c == NC) {
    float s = 0.f;
#pragma unroll
    for (int k = 0; k < NSLOT; ++k) s += ip[(size_t)k * NQ + q];
    out[(size_t)NQ * NC + q] = s;
  }
}

extern "C" void kernel_launch(void* const* d_in, const int* in_sizes, int n_in,
                              void* d_out, int out_size, void* d_ws, size_t ws_size,
                              hipStream_t stream) {
  const float* feat = (const float*)d_in[0];  // [8192][256]
  const float* exf  = (const float*)d_in[1];  // [16384][256]
  const float* exc  = (const float*)d_in[2];  // [16384][28]
  float* out = (float*)d_out;
  char* ws = (char*)d_ws;
  // ws layout (bytes): qn 4MB | kn 8MB | vt 1MB | ep 16MB | ip 512KB  (~29.5MB)
  u16* qn = (u16*)ws;
  u16* kn = (u16*)(ws + 4194304);
  u16* vt = (u16*)(ws + 12582912);
  float* ep = (float*)(ws + 13631488);
  float* ip = (float*)(ws + 30408704);

  norm_kernel<<<dim3(NQ / 4), dim3(256), 0, stream>>>(feat, qn, NQ);
  norm_kernel<<<dim3(ND / 4), dim3(256), 0, stream>>>(exf, kn, ND);
  vt_kernel<<<dim3(ND / 256), dim3(256), 0, stream>>>(exc, vt);
  fused_kernel<<<dim3(512), dim3(256), 0, stream>>>(qn, kn, vt, ep, ip);
  reduce_kernel<<<dim3(NQ * 32 / 256), dim3(256), 0, stream>>>(ep, ip, out);
}

// Round 4
// 129.143 us; speedup vs baseline: 1.7115x; 1.0406x over previous
//
#include <hip/hip_runtime.h>
#include <stdint.h>

// minerva2: echo = (F̂ Ê^T)^3 @ V, intensity = rowsum((F̂ Ê^T)^3)
// R4: Q-in-registers (1x4 wave grid), XCD-aware dchunk mapping (K L2-resident),
// intensity as ones-column of Vt (PV MFMA computes it for free).

typedef unsigned short u16;
typedef __bf16 bf16x8 __attribute__((ext_vector_type(8)));
typedef float f32x4 __attribute__((ext_vector_type(4)));
typedef unsigned short u16x4 __attribute__((ext_vector_type(4)));

#define NQ 8192
#define ND 16384
#define NH 256
#define NC 28
#define DCHUNK 2048
#define NDT 16       // 128-row D-tiles per chunk
#define NSLOT 8      // partial slots = 8 D-chunks (one per XCD)

__device__ __forceinline__ u16 f2bf(float f) {
  unsigned u = __builtin_bit_cast(unsigned, f);
  u += 0x7fffu + ((u >> 16) & 1u);   // RNE
  return (u16)(u >> 16);
}

__device__ __forceinline__ void gload16(const void* g, void* l) {
  // async global->LDS, 16B/lane; LDS dest = wave-uniform base + lane*16
  __builtin_amdgcn_global_load_lds(
      (__attribute__((address_space(1))) void*)g,
      (__attribute__((address_space(3))) void*)l, 16, 0, 0);
}

// ---------------- normalize rows of [rows][256] f32 -> bf16 ----------------
__global__ __launch_bounds__(256) void norm_kernel(const float* __restrict__ in,
                                                   u16* __restrict__ out, int rows) {
  const int wid = threadIdx.x >> 6, lane = threadIdx.x & 63;
  const int row = blockIdx.x * 4 + wid;
  if (row >= rows) return;
  const float4* p = (const float4*)(in + (size_t)row * NH);
  float4 v = p[lane];
  float ss = v.x * v.x + v.y * v.y + v.z * v.z + v.w * v.w;
#pragma unroll
  for (int m = 1; m <= 32; m <<= 1) ss += __shfl_xor(ss, m, 64);
  const float sc = 1.0f / fmaxf(sqrtf(ss), 1e-12f);  // matches F.normalize eps
  u16x4 o;
  o.x = f2bf(v.x * sc); o.y = f2bf(v.y * sc);
  o.z = f2bf(v.z * sc); o.w = f2bf(v.w * sc);
  *(u16x4*)(out + (size_t)row * NH + lane * 4) = o;
}

// ---- V [16384][28] f32 -> Vt [32][16384] bf16; col 28 = 1.0 (intensity) ---
__global__ __launch_bounds__(256) void vt_kernel(const float* __restrict__ V,
                                                 u16* __restrict__ Vt) {
  const int d = blockIdx.x * 256 + threadIdx.x;  // 16384
#pragma unroll
  for (int c = 0; c < NC; ++c) Vt[(size_t)c * ND + d] = f2bf(V[(size_t)d * NC + c]);
  Vt[(size_t)28 * ND + d] = 0x3F80;  // bf16 1.0 -> echo col 28 == intensity
  Vt[(size_t)29 * ND + d] = 0;
  Vt[(size_t)30 * ND + d] = 0;
  Vt[(size_t)31 * ND + d] = 0;
}

// ---------------- fused main kernel ----------------------------------------
// grid 512: dch = bid&7 (-> XCD), ntile = bid>>3. 256 thr = 4 waves, 1x4 grid:
// wave w owns rows [ntile*128 + w*32, +32) x all 128 D-cols of the tile.
// Q A-frags (whole H) live in registers. LDS: K dbuf 2x16KB + 4x8KB stash.
__global__ __launch_bounds__(256, 2) void fused_kernel(
    const u16* __restrict__ Qn, const u16* __restrict__ Kn,
    const u16* __restrict__ Vt, float* __restrict__ ep) {
  __shared__ alignas(16) char smem[65536];
  const int tid = threadIdx.x;
  const int wid = tid >> 6;
  const int lane = tid & 63;
  const int l16 = lane & 15;
  const int lg = lane >> 4;
  const int dch = blockIdx.x & 7;       // XCD-aware: one D-chunk per XCD
  const int ntile = blockIdx.x >> 3;
  const int qbase = ntile * 128;
  const int rowbase = qbase + wid * 32;

  // ---- Q fragments, all H, in registers: qA[mb][kstep], kstep = 32-wide ----
  bf16x8 qA[2][8];
#pragma unroll
  for (int mb = 0; mb < 2; ++mb)
#pragma unroll
    for (int ks = 0; ks < 8; ++ks)
      qA[mb][ks] = *(const bf16x8*)(Qn + (size_t)(rowbase + mb * 16 + l16) * NH +
                                    ks * 32 + lg * 8);

  f32x4 eacc[2][2];
#pragma unroll
  for (int mb = 0; mb < 2; ++mb) {
    eacc[mb][0] = f32x4{0.f, 0.f, 0.f, 0.f};
    eacc[mb][1] = f32x4{0.f, 0.f, 0.f, 0.f};
  }
  f32x4 sacc[2][8];

  // stage one 64-wide H-slab of the K-tile (128 rows) into buf.
  // LDS linear dest; source chunk pre-swizzled: c8 ^= row&7 (rule #21).
  auto stageK = [&](int buf, int h0, const u16* kt) {
#pragma unroll
    for (int r = 0; r < 4; ++r) {
      const int row = r * 32 + (tid >> 3);
      const int c8 = (tid & 7) ^ (row & 7);
      gload16(kt + (size_t)row * NH + h0 + c8 * 8,
              smem + buf * 16384 + r * 4096 + wid * 1024);
    }
  };

  const u16* kc = Kn + (size_t)dch * DCHUNK * NH;
  stageK(0, 0, kc);
  __syncthreads();

  for (int t = 0; t < NDT; ++t) {
    const u16* kt = kc + (size_t)t * 128 * NH;
#pragma unroll
    for (int mb = 0; mb < 2; ++mb)
#pragma unroll
      for (int nb = 0; nb < 8; ++nb) sacc[mb][nb] = f32x4{0.f, 0.f, 0.f, 0.f};

#pragma unroll
    for (int ks = 0; ks < 4; ++ks) {
      if (ks < 3) stageK((ks + 1) & 1, (ks + 1) * 64, kt);
      else if (t < NDT - 1) stageK(0, 0, kt + 128 * NH);
      const char* kbuf = smem + (ks & 1) * 16384;
#pragma unroll
      for (int k2 = 0; k2 < 2; ++k2) {
        bf16x8 B[8];
#pragma unroll
        for (int nb = 0; nb < 8; ++nb)
          B[nb] = *(const bf16x8*)(kbuf + (nb * 16 + l16) * 128 +
                                   (((k2 * 4 + lg) ^ (l16 & 7)) << 4));
#pragma unroll
        for (int mb = 0; mb < 2; ++mb)
#pragma unroll
          for (int nb = 0; nb < 8; ++nb)
            sacc[mb][nb] = __builtin_amdgcn_mfma_f32_16x16x32_bf16(
                qA[mb][ks * 2 + k2], B[nb], sacc[mb][nb], 0, 0, 0);
      }
      __syncthreads();
    }

    // ---- cube (fp32) -> bf16 stash (wave-private, swizzled) ----
    char* sb = smem + 32768 + wid * 8192;  // [32 rows][256B], chunk ^= row&15
#pragma unroll
    for (int mb = 0; mb < 2; ++mb)
#pragma unroll
      for (int nb = 0; nb < 8; ++nb) {
        f32x4 s = sacc[mb][nb];
        f32x4 a3 = s * s * s;
#pragma unroll
        for (int r = 0; r < 4; ++r) {
          const int row = mb * 16 + lg * 4 + r;   // C/D: row=(lane>>4)*4+reg
          const int col = nb * 16 + l16;          //      col=lane&15
          *(u16*)(sb + row * 256 + (((col >> 3) ^ (row & 15)) << 4) +
                  (col & 7) * 2) = f2bf(a3[r]);
        }
      }

    // ---- PV: echo[q, c] += a[q, d] * Vt^T[d, c]  (intensity = col 28) ----
    const int dbase = dch * DCHUNK + t * 128;
#pragma unroll
    for (int mb = 0; mb < 2; ++mb) {
      const int arow = mb * 16 + l16;
#pragma unroll
      for (int dk = 0; dk < 4; ++dk) {
        const bf16x8 aA =
            *(const bf16x8*)(sb + arow * 256 + (((dk * 4 + lg) ^ l16) << 4));
#pragma unroll
        for (int cn = 0; cn < 2; ++cn) {
          const bf16x8 vB = *(const bf16x8*)(Vt + (size_t)(cn * 16 + l16) * ND +
                                             dbase + dk * 32 + lg * 8);
          eacc[mb][cn] = __builtin_amdgcn_mfma_f32_16x16x32_bf16(
              aA, vB, eacc[mb][cn], 0, 0, 0);
        }
      }
    }
    // no barrier: stash is wave-private; K bufs protected by ks-loop barriers
  }

  // ---- epilogue: write partials (slot = dch), no cross-wave merge ----
#pragma unroll
  for (int mb = 0; mb < 2; ++mb)
#pragma unroll
    for (int cn = 0; cn < 2; ++cn)
#pragma unroll
      for (int r = 0; r < 4; ++r) {
        const int row = rowbase + mb * 16 + lg * 4 + r;
        ep[((size_t)dch * NQ + row) * 32 + cn * 16 + l16] = eacc[mb][cn][r];
      }
}

// ---------------- reduce 8 partial slots -> d_out --------------------------
__global__ __launch_bounds__(256) void reduce_kernel(const float* __restrict__ ep,
                                                     float* __restrict__ out) {
  const int g = blockIdx.x * 256 + threadIdx.x;  // 8192*32
  const int q = g >> 5, c = g & 31;
  if (c < NC) {
    float s = 0.f;
#pragma unroll
    for (int k = 0; k < NSLOT; ++k) s += ep[((size_t)k * NQ + q) * 32 + c];
    out[(size_t)q * NC + c] = s;
  } else if (c == NC) {  // ones-column == intensity
    float s = 0.f;
#pragma unroll
    for (int k = 0; k < NSLOT; ++k) s += ep[((size_t)k * NQ + q) * 32 + NC];
    out[(size_t)NQ * NC + q] = s;
  }
}

extern "C" void kernel_launch(void* const* d_in, const int* in_sizes, int n_in,
                              void* d_out, int out_size, void* d_ws, size_t ws_size,
                              hipStream_t stream) {
  const float* feat = (const float*)d_in[0];  // [8192][256]
  const float* exf  = (const float*)d_in[1];  // [16384][256]
  const float* exc  = (const float*)d_in[2];  // [16384][28]
  float* out = (float*)d_out;
  char* ws = (char*)d_ws;
  // ws layout: qn 4MB | kn 8MB | vt 1MB | ep 8MB  (~21MB)
  u16* qn = (u16*)ws;
  u16* kn = (u16*)(ws + 4194304);
  u16* vt = (u16*)(ws + 12582912);
  float* ep = (float*)(ws + 13631488);

  norm_kernel<<<dim3(NQ / 4), dim3(256), 0, stream>>>(feat, qn, NQ);
  norm_kernel<<<dim3(ND / 4), dim3(256), 0, stream>>>(exf, kn, ND);
  vt_kernel<<<dim3(ND / 256), dim3(256), 0, stream>>>(exc, vt);
  fused_kernel<<<dim3(512), dim3(256), 0, stream>>>(qn, kn, vt, ep);
  reduce_kernel<<<dim3(NQ * 32 / 256), dim3(256), 0, stream>>>(ep, out);
}

// Round 5
// 106.197 us; speedup vs baseline: 2.0813x; 1.2161x over previous
//
#include <hip/hip_runtime.h>
#include <stdint.h>

// minerva2: echo = (F̂ Ê^T)^3 @ V, intensity = rowsum((F̂ Ê^T)^3)
// R5 = R4 (Q-in-reg, XCD-aware dch, ones-column intensity) +
//   32KB LDS (stash aliases Kbuf1, PV split in 2 halves) + grid 1024
//   -> 4 blocks/CU for latency hiding.

typedef unsigned short u16;
typedef __bf16 bf16x8 __attribute__((ext_vector_type(8)));
typedef float f32x4 __attribute__((ext_vector_type(4)));
typedef unsigned short u16x4 __attribute__((ext_vector_type(4)));

#define NQ 8192
#define ND 16384
#define NH 256
#define NC 28
#define DCHUNK 1024
#define NDT 8        // 128-row D-tiles per chunk
#define NSLOT 16     // partial slots = 16 D-chunks

__device__ __forceinline__ u16 f2bf(float f) {
  unsigned u = __builtin_bit_cast(unsigned, f);
  u += 0x7fffu + ((u >> 16) & 1u);   // RNE
  return (u16)(u >> 16);
}

__device__ __forceinline__ void gload16(const void* g, void* l) {
  // async global->LDS, 16B/lane; LDS dest = wave-uniform base + lane*16
  __builtin_amdgcn_global_load_lds(
      (__attribute__((address_space(1))) void*)g,
      (__attribute__((address_space(3))) void*)l, 16, 0, 0);
}

// ---------------- normalize rows of [rows][256] f32 -> bf16 ----------------
__global__ __launch_bounds__(256) void norm_kernel(const float* __restrict__ in,
                                                   u16* __restrict__ out, int rows) {
  const int wid = threadIdx.x >> 6, lane = threadIdx.x & 63;
  const int row = blockIdx.x * 4 + wid;
  if (row >= rows) return;
  const float4* p = (const float4*)(in + (size_t)row * NH);
  float4 v = p[lane];
  float ss = v.x * v.x + v.y * v.y + v.z * v.z + v.w * v.w;
#pragma unroll
  for (int m = 1; m <= 32; m <<= 1) ss += __shfl_xor(ss, m, 64);
  const float sc = 1.0f / fmaxf(sqrtf(ss), 1e-12f);  // matches F.normalize eps
  u16x4 o;
  o.x = f2bf(v.x * sc); o.y = f2bf(v.y * sc);
  o.z = f2bf(v.z * sc); o.w = f2bf(v.w * sc);
  *(u16x4*)(out + (size_t)row * NH + lane * 4) = o;
}

// ---- V [16384][28] f32 -> Vt [32][16384] bf16; col 28 = 1.0 (intensity) ---
__global__ __launch_bounds__(256) void vt_kernel(const float* __restrict__ V,
                                                 u16* __restrict__ Vt) {
  const int d = blockIdx.x * 256 + threadIdx.x;  // 16384
#pragma unroll
  for (int c = 0; c < NC; ++c) Vt[(size_t)c * ND + d] = f2bf(V[(size_t)d * NC + c]);
  Vt[(size_t)28 * ND + d] = 0x3F80;  // bf16 1.0 -> echo col 28 == intensity
  Vt[(size_t)29 * ND + d] = 0;
  Vt[(size_t)30 * ND + d] = 0;
  Vt[(size_t)31 * ND + d] = 0;
}

// ---------------- fused main kernel ----------------------------------------
// grid 1024: dch = bid&15 (XCD-local pair of chunks), ntile = bid>>4.
// 256 thr = 4 waves, 1x4 grid: wave w owns rows [ntile*128+w*32, +32).
// Q A-frags in registers. LDS 32KB: Kbuf0 [0,16K), Kbuf1 [16K,32K);
// a-stash aliases Kbuf1 during PV (4KB/wave), PV in two 64-d halves.
__global__ __launch_bounds__(256, 2) void fused_kernel(
    const u16* __restrict__ Qn, const u16* __restrict__ Kn,
    const u16* __restrict__ Vt, float* __restrict__ ep) {
  __shared__ alignas(16) char smem[32768];
  const int tid = threadIdx.x;
  const int wid = tid >> 6;
  const int lane = tid & 63;
  const int l16 = lane & 15;
  const int lg = lane >> 4;
  const int dch = blockIdx.x & 15;
  const int ntile = blockIdx.x >> 4;
  const int qbase = ntile * 128;
  const int rowbase = qbase + wid * 32;

  // ---- Q fragments, all H, in registers ----
  bf16x8 qA[2][8];
#pragma unroll
  for (int mb = 0; mb < 2; ++mb)
#pragma unroll
    for (int ks = 0; ks < 8; ++ks)
      qA[mb][ks] = *(const bf16x8*)(Qn + (size_t)(rowbase + mb * 16 + l16) * NH +
                                    ks * 32 + lg * 8);

  f32x4 eacc[2][2];
#pragma unroll
  for (int mb = 0; mb < 2; ++mb) {
    eacc[mb][0] = f32x4{0.f, 0.f, 0.f, 0.f};
    eacc[mb][1] = f32x4{0.f, 0.f, 0.f, 0.f};
  }
  f32x4 sacc[2][8];

  // stage one 64-wide H-slab of the K-tile (128 rows) into buf.
  // Linear LDS dest; source chunk pre-swizzled: c8 ^= row&7 (rule #21).
  auto stageK = [&](int buf, int h0, const u16* kt) {
#pragma unroll
    for (int r = 0; r < 4; ++r) {
      const int row = r * 32 + (tid >> 3);
      const int c8 = (tid & 7) ^ (row & 7);
      gload16(kt + (size_t)row * NH + h0 + c8 * 8,
              smem + buf * 16384 + r * 4096 + wid * 1024);
    }
  };

  const u16* kc = Kn + (size_t)dch * DCHUNK * NH;
  stageK(0, 0, kc);
  __syncthreads();

  for (int t = 0; t < NDT; ++t) {
    const u16* kt = kc + (size_t)t * 128 * NH;
#pragma unroll
    for (int mb = 0; mb < 2; ++mb)
#pragma unroll
      for (int nb = 0; nb < 8; ++nb) sacc[mb][nb] = f32x4{0.f, 0.f, 0.f, 0.f};

#pragma unroll
    for (int ks = 0; ks < 4; ++ks) {
      if (ks < 3) stageK((ks + 1) & 1, (ks + 1) * 64, kt);
      else if (t < NDT - 1) stageK(0, 0, kt + 128 * NH);  // next-t slab0 -> buf0
      const char* kbuf = smem + (ks & 1) * 16384;
#pragma unroll
      for (int k2 = 0; k2 < 2; ++k2) {
        bf16x8 B[8];
#pragma unroll
        for (int nb = 0; nb < 8; ++nb)
          B[nb] = *(const bf16x8*)(kbuf + (nb * 16 + l16) * 128 +
                                   (((k2 * 4 + lg) ^ (l16 & 7)) << 4));
#pragma unroll
        for (int mb = 0; mb < 2; ++mb)
#pragma unroll
          for (int nb = 0; nb < 8; ++nb)
            sacc[mb][nb] = __builtin_amdgcn_mfma_f32_16x16x32_bf16(
                qA[mb][ks * 2 + k2], B[nb], sacc[mb][nb], 0, 0, 0);
      }
      __syncthreads();
    }
    // After ks=3 barrier: buf1 fully consumed; prefetch (if any) went to buf0.
    // Kbuf1 region [16K,32K) is now the per-wave a-stash (4KB each).

    const int dbase = dch * DCHUNK + t * 128;
    char* sb = smem + 16384 + wid * 4096;  // [32 rows][128B], chunk ^= row&7

#pragma unroll
    for (int half = 0; half < 2; ++half) {
      // cube (fp32) -> bf16 stash for this 64-d half
#pragma unroll
      for (int mb = 0; mb < 2; ++mb)
#pragma unroll
        for (int nb2 = 0; nb2 < 4; ++nb2) {
          f32x4 s = sacc[mb][half * 4 + nb2];
          f32x4 a3 = s * s * s;
#pragma unroll
          for (int r = 0; r < 4; ++r) {
            const int row = mb * 16 + lg * 4 + r;   // C/D: row=(lane>>4)*4+reg
            const int col = nb2 * 16 + l16;         //      col=lane&15 (in-half)
            *(u16*)(sb + row * 128 + (((col >> 3) ^ (row & 7)) << 4) +
                    (col & 7) * 2) = f2bf(a3[r]);
          }
        }

      // PV for this half: echo[q,c] += a[q,d] * Vt^T[d,c] (intensity = col 28)
#pragma unroll
      for (int mb = 0; mb < 2; ++mb) {
        const int arow = mb * 16 + l16;
#pragma unroll
        for (int dk = 0; dk < 2; ++dk) {
          const bf16x8 aA =
              *(const bf16x8*)(sb + arow * 128 + (((dk * 4 + lg) ^ (arow & 7)) << 4));
#pragma unroll
          for (int cn = 0; cn < 2; ++cn) {
            const bf16x8 vB = *(const bf16x8*)(Vt + (size_t)(cn * 16 + l16) * ND +
                                               dbase + half * 64 + dk * 32 + lg * 8);
            eacc[mb][cn] = __builtin_amdgcn_mfma_f32_16x16x32_bf16(
                aA, vB, eacc[mb][cn], 0, 0, 0);
          }
        }
      }
    }
    __syncthreads();  // stash region must be free before next t stages buf1
  }

  // ---- epilogue: write partials (slot = dch) ----
#pragma unroll
  for (int mb = 0; mb < 2; ++mb)
#pragma unroll
    for (int cn = 0; cn < 2; ++cn)
#pragma unroll
      for (int r = 0; r < 4; ++r) {
        const int row = rowbase + mb * 16 + lg * 4 + r;
        ep[((size_t)dch * NQ + row) * 32 + cn * 16 + l16] = eacc[mb][cn][r];
      }
}

// ---------------- reduce 16 partial slots -> d_out -------------------------
__global__ __launch_bounds__(256) void reduce_kernel(const float* __restrict__ ep,
                                                     float* __restrict__ out) {
  const int g = blockIdx.x * 256 + threadIdx.x;  // 8192*32
  const int q = g >> 5, c = g & 31;
  if (c < NC) {
    float s = 0.f;
#pragma unroll
    for (int k = 0; k < NSLOT; ++k) s += ep[((size_t)k * NQ + q) * 32 + c];
    out[(size_t)q * NC + c] = s;
  } else if (c == NC) {  // ones-column == intensity
    float s = 0.f;
#pragma unroll
    for (int k = 0; k < NSLOT; ++k) s += ep[((size_t)k * NQ + q) * 32 + NC];
    out[(size_t)NQ * NC + q] = s;
  }
}

extern "C" void kernel_launch(void* const* d_in, const int* in_sizes, int n_in,
                              void* d_out, int out_size, void* d_ws, size_t ws_size,
                              hipStream_t stream) {
  const float* feat = (const float*)d_in[0];  // [8192][256]
  const float* exf  = (const float*)d_in[1];  // [16384][256]
  const float* exc  = (const float*)d_in[2];  // [16384][28]
  float* out = (float*)d_out;
  char* ws = (char*)d_ws;
  // ws layout: qn 4MB | kn 8MB | vt 1MB | ep 16MB  (~29MB)
  u16* qn = (u16*)ws;
  u16* kn = (u16*)(ws + 4194304);
  u16* vt = (u16*)(ws + 12582912);
  float* ep = (float*)(ws + 13631488);

  norm_kernel<<<dim3(NQ / 4), dim3(256), 0, stream>>>(feat, qn, NQ);
  norm_kernel<<<dim3(ND / 4), dim3(256), 0, stream>>>(exf, kn, ND);
  vt_kernel<<<dim3(ND / 256), dim3(256), 0, stream>>>(exc, vt);
  fused_kernel<<<dim3(1024), dim3(256), 0, stream>>>(qn, kn, vt, ep);
  reduce_kernel<<<dim3(NQ * 32 / 256), dim3(256), 0, stream>>>(ep, out);
}